// Round 1
// baseline (127.740 us; speedup 1.0000x reference)
//
#include <hip/hip_runtime.h>

#define H0 128
#define W0 512
// Exactly mirror the Python double-precision constants.
__device__ __host__ constexpr double DXd() { return 0.00859375; }
__device__ __host__ constexpr double Fd()  { return 8.0; }
__device__ __host__ constexpr double OXd() { return 5.5 / 2.0; }
__device__ __host__ constexpr double OYd() { return 7.7 / 2.0; }

// Build the 128x512 int32 distortion LUT in double precision (matches numpy f64).
__global__ void build_bn_kernel(int* __restrict__ bn) {
    int idx = blockIdx.x * blockDim.x + threadIdx.x;
    if (idx >= H0 * W0) return;
    int j = idx & (W0 - 1);
    int i = idx >> 9;  // /512
    double a0 = atan(DXd() * ((double)j - OXd()) / Fd());
    double c  = cos(a0) - 1.0;
    double v  = trunc((double)i - c * ((double)i - OYd()));
    int b = (int)v;
    b = b < 0 ? 0 : (b > H0 - 1 ? H0 - 1 : b);
    bn[idx] = b;
}

// out[plane, i, j] = x[plane, bn[i,j], j]; 4 floats per thread.
__global__ void gather_kernel(const float* __restrict__ x,
                              const int* __restrict__ bn,
                              float* __restrict__ out) {
    long long tid = (long long)blockIdx.x * blockDim.x + threadIdx.x;
    // total float4 units = 16*64*128*512/4 = 2^24
    int ij    = (int)(tid & ((H0 * W0 / 4) - 1)); // within-plane float4 idx (2^14)
    int plane = (int)(tid >> 14);                 // 0..1023
    int j4 = ij & (W0 / 4 - 1);                   // 0..127
    int i  = ij >> 7;                             // 0..127
    const float* xp = x + (long long)plane * (H0 * W0);
    int j = j4 * 4;
    int4 b4 = *reinterpret_cast<const int4*>(bn + i * W0 + j);
    float4 o;
    o.x = xp[b4.x * W0 + j + 0];
    o.y = xp[b4.y * W0 + j + 1];
    o.z = xp[b4.z * W0 + j + 2];
    o.w = xp[b4.w * W0 + j + 3];
    reinterpret_cast<float4*>(out)[tid] = o;
}

// Fallback if ws is too small: compute bn per element in f64 (slow but correct).
__global__ void gather_fb_kernel(const float* __restrict__ x,
                                 float* __restrict__ out) {
    long long tid = (long long)blockIdx.x * blockDim.x + threadIdx.x;
    int ij    = (int)(tid & ((H0 * W0 / 4) - 1));
    int plane = (int)(tid >> 14);
    int j4 = ij & (W0 / 4 - 1);
    int i  = ij >> 7;
    const float* xp = x + (long long)plane * (H0 * W0);
    float4 o;
    float* op = &o.x;
    #pragma unroll
    for (int k = 0; k < 4; ++k) {
        int j = j4 * 4 + k;
        double a0 = atan(DXd() * ((double)j - OXd()) / Fd());
        double c  = cos(a0) - 1.0;
        double v  = trunc((double)i - c * ((double)i - OYd()));
        int b = (int)v;
        b = b < 0 ? 0 : (b > H0 - 1 ? H0 - 1 : b);
        op[k] = xp[b * W0 + j];
    }
    reinterpret_cast<float4*>(out)[tid] = o;
}

extern "C" void kernel_launch(void* const* d_in, const int* in_sizes, int n_in,
                              void* d_out, int out_size, void* d_ws, size_t ws_size,
                              hipStream_t stream) {
    const float* x = (const float*)d_in[0];
    float* out = (float*)d_out;

    const long long total_vec4 = (long long)16 * 64 * H0 * W0 / 4;  // 2^24
    const int block = 256;
    const int grid_gather = (int)(total_vec4 / block);              // 65536

    if (ws_size >= (size_t)(H0 * W0 * sizeof(int))) {
        int* bn = (int*)d_ws;
        build_bn_kernel<<<(H0 * W0 + block - 1) / block, block, 0, stream>>>(bn);
        gather_kernel<<<grid_gather, block, 0, stream>>>(x, bn, out);
    } else {
        gather_fb_kernel<<<grid_gather, block, 0, stream>>>(x, out);
    }
}

// Round 2
// 119.659 us; speedup vs baseline: 1.0675x; 1.0675x over previous
//
#include <hip/hip_runtime.h>

#define H0 128
#define W0 512
#define NPLANES (16 * 64)

// ---------------------------------------------------------------------------
// Step 1: bn table as uchar (rows fit in 7 bits), computed in f64 to exactly
// match numpy's float64 trunc boundaries.
// ---------------------------------------------------------------------------
__global__ void build_bn8_kernel(unsigned char* __restrict__ bn8) {
    int idx = blockIdx.x * blockDim.x + threadIdx.x;  // 0..65535
    if (idx >= H0 * W0) return;
    int j = idx & (W0 - 1);
    int i = idx >> 9;
    double a0 = atan(0.00859375 * ((double)j - (5.5 / 2.0)) / 8.0);
    double c  = cos(a0) - 1.0;
    double v  = trunc((double)i - c * ((double)i - (7.7 / 2.0)));
    int b = (int)v;
    b = b < 0 ? 0 : (b > H0 - 1 ? H0 - 1 : b);
    bn8[idx] = (unsigned char)b;
}

// ---------------------------------------------------------------------------
// Step 2: per-row compacted quad worklist.
// Row i has 128 quads (4 cols each). Entry (ushort):
//   uniform quad: (j4<<7) | src          (bit15 = 0)
//   mixed quad:   0x8000 | (j4<<7)       (bit15 = 1)
// Ordered compaction: uniform quads first (j4 ascending), mixed at the tail.
// Entries are stored INTERLEAVED so that the dword at lane l contains
// positions {l, l+64}: pos p -> ushort index (p<64 ? 2p : 2(p-64)+1).
// Since nUniform >= ~110 per row, all mixed entries land in slot 1 ->
// slot-0 iterations are divergence-free.
// ---------------------------------------------------------------------------
__global__ void build_rowlist_kernel(const unsigned char* __restrict__ bn8,
                                     unsigned short* __restrict__ rowlist) {
    int i = blockIdx.x;        // row 0..127
    int t = threadIdx.x;       // quad 0..127
    const unsigned char* r = bn8 + i * W0;
    int j = t * 4;
    unsigned b0 = r[j], b1 = r[j + 1], b2 = r[j + 2], b3 = r[j + 3];
    bool uni = (b0 == b1) && (b1 == b2) && (b2 == b3);

    __shared__ int waveU[2];
    unsigned long long m = __ballot(uni);
    int lane = t & 63;
    int wave = t >> 6;
    int pre  = __popcll(m & ((1ull << lane) - 1ull));  // uniform before me in wave
    int wtot = __popcll(m);
    if (lane == 0) waveU[wave] = wtot;
    __syncthreads();
    int u0 = waveU[0], u1 = waveU[1];
    int nU = u0 + u1;
    int pos;
    if (uni) {
        pos = pre + (wave ? u0 : 0);
    } else {
        pos = nU + (lane - pre) + (wave ? (64 - u0) : 0);
    }
    unsigned short e = uni ? (unsigned short)((t << 7) | (int)b0)
                           : (unsigned short)(0x8000u | (unsigned)(t << 7));
    int loc = (pos < 64) ? (2 * pos) : (2 * (pos - 64) + 1);
    rowlist[i * 128 + loc] = e;
}

// ---------------------------------------------------------------------------
// Step 3: the gather. Block = 256 threads = 4 rows x 64 lanes; each lane
// handles 2 quads of its row (worklist positions {lane, lane+64} via one
// dword load). Fast path: float4 load + float4 store. Mixed path (rare,
// tail slot only): 1 uchar4 bn load + 4 scalar loads.
// ---------------------------------------------------------------------------
__global__ void gather2_kernel(const float* __restrict__ x,
                               const unsigned char* __restrict__ bn8,
                               const unsigned short* __restrict__ rowlist,
                               float* __restrict__ out) {
    int bid = blockIdx.x;
    int plane = bid >> 5;                 // 0..1023
    int rg    = bid & 31;                 // row group of 4
    int t     = threadIdx.x;
    int rsub  = t >> 6;                   // 0..3
    int lane  = t & 63;
    int i = rg * 4 + rsub;

    const float* xp = x + (size_t)plane * (H0 * W0);
    float* op = out + (size_t)plane * (H0 * W0) + (size_t)i * W0;
    const unsigned int* rl = reinterpret_cast<const unsigned int*>(rowlist + i * 128);
    unsigned int L = rl[lane];

    #pragma unroll
    for (int k = 0; k < 2; ++k) {
        unsigned e = (k == 0) ? (L & 0xffffu) : (L >> 16);
        int j4 = (int)((e >> 7) & 127u);
        int j = j4 * 4;
        float4 o;
        if (!(e & 0x8000u)) {
            int src = (int)(e & 127u);
            o = *reinterpret_cast<const float4*>(xp + src * W0 + j);
        } else {
            const unsigned char* bq = bn8 + i * W0 + j;
            o.x = xp[(int)bq[0] * W0 + j + 0];
            o.y = xp[(int)bq[1] * W0 + j + 1];
            o.z = xp[(int)bq[2] * W0 + j + 2];
            o.w = xp[(int)bq[3] * W0 + j + 3];
        }
        *reinterpret_cast<float4*>(op + j) = o;
    }
}

// ---------------------------------------------------------------------------
// Fallback (ws too small): per-element f64 compute, known-correct from R0.
// ---------------------------------------------------------------------------
__global__ void gather_fb_kernel(const float* __restrict__ x,
                                 float* __restrict__ out) {
    long long tid = (long long)blockIdx.x * blockDim.x + threadIdx.x;
    int ij    = (int)(tid & ((H0 * W0 / 4) - 1));
    int plane = (int)(tid >> 14);
    int j4 = ij & (W0 / 4 - 1);
    int i  = ij >> 7;
    const float* xp = x + (long long)plane * (H0 * W0);
    float4 o;
    float* op = &o.x;
    #pragma unroll
    for (int k = 0; k < 4; ++k) {
        int j = j4 * 4 + k;
        double a0 = atan(0.00859375 * ((double)j - (5.5 / 2.0)) / 8.0);
        double c  = cos(a0) - 1.0;
        double v  = trunc((double)i - c * ((double)i - (7.7 / 2.0)));
        int b = (int)v;
        b = b < 0 ? 0 : (b > H0 - 1 ? H0 - 1 : b);
        op[k] = xp[b * W0 + j];
    }
    reinterpret_cast<float4*>(out)[tid] = o;
}

extern "C" void kernel_launch(void* const* d_in, const int* in_sizes, int n_in,
                              void* d_out, int out_size, void* d_ws, size_t ws_size,
                              hipStream_t stream) {
    const float* x = (const float*)d_in[0];
    float* out = (float*)d_out;

    const size_t bn8_bytes = H0 * W0;                 // 64 KiB
    const size_t rl_bytes  = H0 * 128 * sizeof(unsigned short);  // 32 KiB
    if (ws_size >= bn8_bytes + rl_bytes) {
        unsigned char*  bn8 = (unsigned char*)d_ws;
        unsigned short* rl  = (unsigned short*)((char*)d_ws + bn8_bytes);

        build_bn8_kernel<<<(H0 * W0) / 256, 256, 0, stream>>>(bn8);
        build_rowlist_kernel<<<H0, 128, 0, stream>>>(bn8, rl);
        gather2_kernel<<<NPLANES * 32, 256, 0, stream>>>(x, bn8, rl, out);
    } else {
        const long long total_vec4 = (long long)NPLANES * H0 * W0 / 4;
        gather_fb_kernel<<<(int)(total_vec4 / 256), 256, 0, stream>>>(x, out);
    }
}

// Round 3
// 115.327 us; speedup vs baseline: 1.1076x; 1.0376x over previous
//
#include <hip/hip_runtime.h>

#define H0 128
#define W0 512
#define NPLANES 1024      // 16*64
#define PP 4              // planes per gather block
#define PS (H0 * W0)      // plane stride in floats

typedef float f32x4 __attribute__((ext_vector_type(4)));

// ---------------------------------------------------------------------------
// Build (one launch): bn8 table (f64 math, matches numpy) + compacted per-row
// quad worklist. Entry (dword):
//   [6:0] src  [13:7] src2  [15:14] split  [22:16] j4  [23] mixed-flag
// uniform quads first (positions 0..nU-1), mixed at tail; position p stored at
// interleaved dword index (p<64 ? 2p : 2(p-64)+1) so lane l's uint2 load gives
// entries for positions {l, l+64}. nU >= ~112 per row -> slot0 divergence-free.
// ---------------------------------------------------------------------------
__global__ void build_tables_kernel(unsigned char* __restrict__ bn8,
                                    unsigned int* __restrict__ rowlist) {
    int i = blockIdx.x;        // row 0..127
    int t = threadIdx.x;       // quad 0..127
    int j0 = t * 4;
    int b[4];
    #pragma unroll
    for (int k = 0; k < 4; ++k) {
        int j = j0 + k;
        double a0 = atan(0.00859375 * ((double)j - (5.5 / 2.0)) / 8.0);
        double c  = cos(a0) - 1.0;
        double v  = trunc((double)i - c * ((double)i - (7.7 / 2.0)));
        int bi = (int)v;
        bi = bi < 0 ? 0 : (bi > H0 - 1 ? H0 - 1 : bi);
        b[k] = bi;
        bn8[i * W0 + j] = (unsigned char)bi;
    }
    bool uni = (b[0] == b[1]) && (b[1] == b[2]) && (b[2] == b[3]);

    __shared__ int waveU[2];
    unsigned long long m = __ballot(uni);
    int lane = t & 63;
    int wave = t >> 6;
    int pre  = __popcll(m & ((1ull << lane) - 1ull));
    if (lane == 0) waveU[wave] = __popcll(m);
    __syncthreads();
    int u0 = waveU[0], u1 = waveU[1];
    int nU = u0 + u1;
    int pos = uni ? (pre + (wave ? u0 : 0))
                  : (nU + (lane - pre) + (wave ? (64 - u0) : 0));

    unsigned e;
    if (uni) {
        e = (unsigned)b[0] | ((unsigned)t << 16);
    } else {
        int split = (b[1] != b[0]) ? 1 : (b[2] != b[0]) ? 2 : 3;
        bool ok = (b[1] == ((1 < split) ? b[0] : b[3])) &&
                  (b[2] == ((2 < split) ? b[0] : b[3]));
        if (!ok) split = 0;   // split==0 -> scalar fallback path in gather
        e = (unsigned)b[0] | ((unsigned)b[3] << 7) | ((unsigned)split << 14)
            | ((unsigned)t << 16) | (1u << 23);
    }
    int loc = (pos < 64) ? (2 * pos) : (2 * (pos - 64) + 1);
    rowlist[i * 128 + loc] = e;
}

// ---------------------------------------------------------------------------
// Gather: block = 256 threads = 4 rows x 64 lanes, PP planes per block.
// XCD swizzle: all 32 rowgroups of a plane-group stay on one XCD so row
// overlap between rowgroups is an L2 hit, not an HBM refetch.
// ---------------------------------------------------------------------------
__global__ void gather3_kernel(const float* __restrict__ x,
                               const unsigned char* __restrict__ bn8,
                               const unsigned int* __restrict__ rowlist,
                               float* __restrict__ out) {
    int bid = blockIdx.x;           // 0..8191
    int xcd = bid & 7;
    int idx = bid >> 3;             // 0..1023
    int pg  = (xcd << 5) + (idx >> 5);  // plane group 0..255, contiguous per XCD
    int rg  = idx & 31;
    int t    = threadIdx.x;
    int rsub = t >> 6;
    int lane = t & 63;
    int i = rg * 4 + rsub;

    const float* xp = x   + (size_t)pg * PP * PS;
    float*       op = out + (size_t)pg * PP * PS + (size_t)i * W0;
    uint2 e2 = *reinterpret_cast<const uint2*>(rowlist + i * 128 + lane * 2);

    #pragma unroll
    for (int k = 0; k < 2; ++k) {
        unsigned e = k ? e2.y : e2.x;
        int j = (int)((e >> 16) & 127u) * 4;
        if (!(e & (1u << 23))) {
            // uniform quad: one float4 per plane
            int src = (int)(e & 127u);
            const f32x4* s = reinterpret_cast<const f32x4*>(xp + src * W0 + j);
            #pragma unroll
            for (int pp = 0; pp < PP; ++pp) {
                f32x4 v = s[pp * (PS / 4)];
                __builtin_nontemporal_store(
                    v, reinterpret_cast<f32x4*>(op + pp * PS + j));
            }
        } else {
            int split = (int)((e >> 14) & 3u);
            if (split) {
                // mixed quad = two rows + split: 2 loads + blend
                int src  = (int)(e & 127u);
                int src2 = (int)((e >> 7) & 127u);
                const f32x4* sa = reinterpret_cast<const f32x4*>(xp + src  * W0 + j);
                const f32x4* sb = reinterpret_cast<const f32x4*>(xp + src2 * W0 + j);
                #pragma unroll
                for (int pp = 0; pp < PP; ++pp) {
                    f32x4 a = sa[pp * (PS / 4)];
                    f32x4 b = sb[pp * (PS / 4)];
                    f32x4 v;
                    v[0] = a[0];
                    v[1] = (split > 1) ? a[1] : b[1];
                    v[2] = (split > 2) ? a[2] : b[2];
                    v[3] = b[3];
                    __builtin_nontemporal_store(
                        v, reinterpret_cast<f32x4*>(op + pp * PS + j));
                }
            } else {
                // safety fallback (should never trigger): 4 scalar loads
                const unsigned char* bq = bn8 + i * W0 + j;
                #pragma unroll
                for (int pp = 0; pp < PP; ++pp) {
                    const float* xq = xp + pp * PS;
                    f32x4 v;
                    v[0] = xq[(int)bq[0] * W0 + j + 0];
                    v[1] = xq[(int)bq[1] * W0 + j + 1];
                    v[2] = xq[(int)bq[2] * W0 + j + 2];
                    v[3] = xq[(int)bq[3] * W0 + j + 3];
                    __builtin_nontemporal_store(
                        v, reinterpret_cast<f32x4*>(op + pp * PS + j));
                }
            }
        }
    }
}

// ---------------------------------------------------------------------------
// Fallback (ws too small): per-element f64 compute, known-correct from R0.
// ---------------------------------------------------------------------------
__global__ void gather_fb_kernel(const float* __restrict__ x,
                                 float* __restrict__ out) {
    long long tid = (long long)blockIdx.x * blockDim.x + threadIdx.x;
    int ij    = (int)(tid & ((H0 * W0 / 4) - 1));
    int plane = (int)(tid >> 14);
    int j4 = ij & (W0 / 4 - 1);
    int i  = ij >> 7;
    const float* xp = x + (long long)plane * PS;
    float4 o;
    float* opp = &o.x;
    #pragma unroll
    for (int k = 0; k < 4; ++k) {
        int j = j4 * 4 + k;
        double a0 = atan(0.00859375 * ((double)j - (5.5 / 2.0)) / 8.0);
        double c  = cos(a0) - 1.0;
        double v  = trunc((double)i - c * ((double)i - (7.7 / 2.0)));
        int b = (int)v;
        b = b < 0 ? 0 : (b > H0 - 1 ? H0 - 1 : b);
        opp[k] = xp[b * W0 + j];
    }
    reinterpret_cast<float4*>(out)[tid] = o;
}

extern "C" void kernel_launch(void* const* d_in, const int* in_sizes, int n_in,
                              void* d_out, int out_size, void* d_ws, size_t ws_size,
                              hipStream_t stream) {
    const float* x = (const float*)d_in[0];
    float* out = (float*)d_out;

    const size_t bn8_bytes = H0 * W0;                         // 64 KiB
    const size_t rl_bytes  = H0 * 128 * sizeof(unsigned int); // 64 KiB
    if (ws_size >= bn8_bytes + rl_bytes) {
        unsigned char* bn8 = (unsigned char*)d_ws;
        unsigned int*  rl  = (unsigned int*)((char*)d_ws + bn8_bytes);

        build_tables_kernel<<<H0, 128, 0, stream>>>(bn8, rl);
        gather3_kernel<<<(NPLANES / PP) * 32, 256, 0, stream>>>(x, bn8, rl, out);
    } else {
        const long long total_vec4 = (long long)NPLANES * H0 * W0 / 4;
        gather_fb_kernel<<<(int)(total_vec4 / 256), 256, 0, stream>>>(x, out);
    }
}

// Round 4
// 86.981 us; speedup vs baseline: 1.4686x; 1.3259x over previous
//
#include <hip/hip_runtime.h>

#define H0 128
#define W0 512
#define NPLANES 1024      // 16*64
#define PP 4              // planes per gather block
#define PS (H0 * W0)      // plane stride in floats

typedef float f32x4 __attribute__((ext_vector_type(4)));

// ---------------------------------------------------------------------------
// bn table as uchar (rows fit 7 bits), f64 math to exactly match numpy trunc.
// 64 KiB; L2-resident for the gather.
// ---------------------------------------------------------------------------
__global__ void build_bn8_kernel(unsigned char* __restrict__ bn8) {
    int idx = blockIdx.x * blockDim.x + threadIdx.x;  // 0..65535
    if (idx >= H0 * W0) return;
    int j = idx & (W0 - 1);
    int i = idx >> 9;
    double a0 = atan(0.00859375 * ((double)j - (5.5 / 2.0)) / 8.0);
    double c  = cos(a0) - 1.0;
    double v  = trunc((double)i - c * ((double)i - (7.7 / 2.0)));
    int b = (int)v;
    b = b < 0 ? 0 : (b > H0 - 1 ? H0 - 1 : b);
    bn8[idx] = (unsigned char)b;
}

// ---------------------------------------------------------------------------
// Gather, natural order: block = 4 rows x 64 lanes, PP planes.
// Lane l handles quads l and l+64 of its row -> wave stores are 1024B
// contiguous. Each quad has <=2 distinct (adjacent) source rows because
// |d bn / d j| <= 0.123: load row bn[j0]; per-lane-predicated second load
// from row bn[j0+3]; per-component select. No divergent fat path, no
// worklist indirection. XCD swizzle keeps a plane-group's 32 rowgroups on
// one XCD so row re-reads are L2 hits.
// ---------------------------------------------------------------------------
__global__ void gather4_kernel(const float* __restrict__ x,
                               const unsigned char* __restrict__ bn8,
                               float* __restrict__ out) {
    int bid = blockIdx.x;               // 0..8191
    int xcd = bid & 7;
    int idx = bid >> 3;                 // 0..1023
    int pg  = (xcd << 5) + (idx >> 5);  // plane-group 0..255, contiguous per XCD
    int rg  = idx & 31;
    int t    = threadIdx.x;
    int rsub = t >> 6;                  // 0..3
    int lane = t & 63;
    int i = rg * 4 + rsub;

    const float* xp = x   + (size_t)pg * PP * PS;
    float*       op = out + (size_t)pg * PP * PS + (size_t)i * W0;
    const unsigned char* bnr = bn8 + i * W0;

    #pragma unroll
    for (int k = 0; k < 2; ++k) {
        int j = 4 * lane + k * 256;
        uchar4 bq = *reinterpret_cast<const uchar4*>(bnr + j);
        int src = bq.x;
        int alt = bq.w;
        bool m1 = (bq.y == bq.x);
        bool m2 = (bq.z == bq.x);
        const float* sa = xp + src * W0 + j;
        const float* sb = xp + alt * W0 + j;
        #pragma unroll
        for (int pp = 0; pp < PP; ++pp) {
            f32x4 a = *reinterpret_cast<const f32x4*>(sa + pp * PS);
            f32x4 b = a;
            if (alt != src) {   // per-lane predicate: masked lanes skip traffic
                b = *reinterpret_cast<const f32x4*>(sb + pp * PS);
            }
            f32x4 v;
            v[0] = a[0];
            v[1] = m1 ? a[1] : b[1];
            v[2] = m2 ? a[2] : b[2];
            v[3] = b[3];        // bq.w==src implies b==a
            __builtin_nontemporal_store(
                v, reinterpret_cast<f32x4*>(op + pp * PS + j));
        }
    }
}

// ---------------------------------------------------------------------------
// Fallback (ws too small): per-element f64 compute, known-correct from R0.
// ---------------------------------------------------------------------------
__global__ void gather_fb_kernel(const float* __restrict__ x,
                                 float* __restrict__ out) {
    long long tid = (long long)blockIdx.x * blockDim.x + threadIdx.x;
    int ij    = (int)(tid & ((H0 * W0 / 4) - 1));
    int plane = (int)(tid >> 14);
    int j4 = ij & (W0 / 4 - 1);
    int i  = ij >> 7;
    const float* xp = x + (long long)plane * PS;
    float4 o;
    float* opp = &o.x;
    #pragma unroll
    for (int k = 0; k < 4; ++k) {
        int j = j4 * 4 + k;
        double a0 = atan(0.00859375 * ((double)j - (5.5 / 2.0)) / 8.0);
        double c  = cos(a0) - 1.0;
        double v  = trunc((double)i - c * ((double)i - (7.7 / 2.0)));
        int b = (int)v;
        b = b < 0 ? 0 : (b > H0 - 1 ? H0 - 1 : b);
        opp[k] = xp[b * W0 + j];
    }
    reinterpret_cast<float4*>(out)[tid] = o;
}

extern "C" void kernel_launch(void* const* d_in, const int* in_sizes, int n_in,
                              void* d_out, int out_size, void* d_ws, size_t ws_size,
                              hipStream_t stream) {
    const float* x = (const float*)d_in[0];
    float* out = (float*)d_out;

    const size_t bn8_bytes = H0 * W0;   // 64 KiB
    if (ws_size >= bn8_bytes) {
        unsigned char* bn8 = (unsigned char*)d_ws;
        build_bn8_kernel<<<(H0 * W0) / 256, 256, 0, stream>>>(bn8);
        gather4_kernel<<<(NPLANES / PP) * 32, 256, 0, stream>>>(x, bn8, out);
    } else {
        const long long total_vec4 = (long long)NPLANES * H0 * W0 / 4;
        gather_fb_kernel<<<(int)(total_vec4 / 256), 256, 0, stream>>>(x, out);
    }
}